// Round 9
// baseline (80955.560 us; speedup 1.0000x reference)
//
#include <hip/hip_runtime.h>
#include <hip/hip_bf16.h>
#include <math.h>

#define DEV static __device__ __forceinline__

DEV float rl(float v, int i){ return __uint_as_float(__builtin_amdgcn_readlane(__float_as_uint(v), i)); }

typedef float f32x16 __attribute__((ext_vector_type(16)));
typedef unsigned long long u64;

// ---- workspace layout (bytes) ----
static constexpr size_t OFF_H     = 0;                    // 8192*1024*4 = 33554432
static constexpr size_t OFF_FEATS = 33554432;             // 8192*5*4    = 163840
static constexpr size_t OFF_BPS   = OFF_FEATS + 163840;   // 8192*5*4 int
static constexpr size_t OFF_FC    = OFF_BPS + 163840;     // 256*5*4
static constexpr size_t OFF_ECH   = OFF_FC + 5120;        // 256*4
static constexpr size_t OFF_EBEST = OFF_ECH + 1024;       // 256
static constexpr size_t OFF_HBUF  = OFF_EBEST + 256;      // 2*1024*8 = 16384
static constexpr size_t OFF_XG    = OFF_HBUF + 16384;     // 2*8192*2048*4
static constexpr size_t XG_BYTES  = 2ull*8192*2048*4;

// =====================================================================
// XG: xg[d][t][row] = emb[t][:] . wih_d[row][:]   (fp32 tiled GEMM)
// =====================================================================
__global__ __launch_bounds__(256) void xg_k(const float* __restrict__ emb,
                                            const float* __restrict__ wihf,
                                            const float* __restrict__ wihb,
                                            float* __restrict__ xg)
{
  const int tm = blockIdx.x * 128;
  const int tn = blockIdx.y * 128;
  const int tid = threadIdx.x;
  const int ty = tid >> 4, tx = tid & 15;
  __shared__ float As[16][132], Bs[16][132];
  float acc[8][8];
  #pragma unroll
  for (int i=0;i<8;i++)
    #pragma unroll
    for (int j=0;j<8;j++) acc[i][j] = 0.f;

  const int m  = tid & 127;
  const int n  = tn + m;
  const float* wih = (n & 2048) ? wihb : wihf;
  const float* arow = emb + (size_t)(tm+m)*768;
  const float* brow = wih + (size_t)(n&2047)*768;
  const int kq = (tid >> 7) << 2;

  for (int k0=0; k0<768; k0+=16){
    #pragma unroll
    for (int r=0;r<2;r++){
      const int kk = kq + r*8;
      float4 v = *reinterpret_cast<const float4*>(arow + k0 + kk);
      As[kk+0][m]=v.x; As[kk+1][m]=v.y; As[kk+2][m]=v.z; As[kk+3][m]=v.w;
      float4 u = *reinterpret_cast<const float4*>(brow + k0 + kk);
      Bs[kk+0][m]=u.x; Bs[kk+1][m]=u.y; Bs[kk+2][m]=u.z; Bs[kk+3][m]=u.w;
    }
    __syncthreads();
    #pragma unroll
    for (int k=0;k<16;k++){
      float4 a0 = *reinterpret_cast<const float4*>(&As[k][ty*8]);
      float4 a1 = *reinterpret_cast<const float4*>(&As[k][ty*8+4]);
      float4 b0 = *reinterpret_cast<const float4*>(&Bs[k][tx*8]);
      float4 b1 = *reinterpret_cast<const float4*>(&Bs[k][tx*8+4]);
      float af[8] = {a0.x,a0.y,a0.z,a0.w,a1.x,a1.y,a1.z,a1.w};
      float bf[8] = {b0.x,b0.y,b0.z,b0.w,b1.x,b1.y,b1.z,b1.w};
      #pragma unroll
      for (int i=0;i<8;i++)
        #pragma unroll
        for (int j=0;j<8;j++) acc[i][j] = fmaf(af[i], bf[j], acc[i][j]);
    }
    __syncthreads();
  }

  const int dd = tn >> 11;
  const int nb = tn & 2047;
  float* xgp = xg + (size_t)dd*8192*2048;
  #pragma unroll
  for (int i=0;i<8;i++){
    float* orow = xgp + (size_t)(tm+ty*8+i)*2048 + nb + tx*8;
    #pragma unroll
    for (int j=0;j<8;j+=4){
      float4 st = { acc[i][j], acc[i][j+1], acc[i][j+2], acc[i][j+3] };
      *reinterpret_cast<float4*>(orow + j) = st;
    }
  }
}

// =====================================================================
// K2 (wave-autonomous): 64 blocks x 512 thr; block (d,k)=(b>>5,b&31);
// wave w of a block FULLY owns 2 hidden units u0=k*16+w*2, u0+1 (8 gate
// rows). Lane l holds h-cols [8l,8l+8) and 8x8 weights (64 VGPR, pinned).
// Per step: 64 FMA -> 6-round shfl_xor butterfly (all 8 row-sums in every
// lane) -> redundant per-lane gate math -> lane0 publishes 2 (tag,h)
// agent-scope pairs, lane1 stores H -> poll own 8 pairs (agent, relaxed).
// NO LDS, NO __syncthreads, no wave-0 serialization: rounds 5/6 showed
// step=1.5us with GEMV+gates only ~0.3us — the residue was barrier
// jitter + wave0-serial segment + MALL RTT; wave drift now overlaps RTT
// with neighbors' compute. Depth-2 slot safety: publishing s+2 requires
// consuming all of s+1, which requires every wave consumed s (every wave
// publishes AND reads full h — proof as round 1). Rounds 7/8's L1/L2
// fast-path abandoned: agent-scope is the evidence-backed channel.
// =====================================================================
__global__ __launch_bounds__(512)
__attribute__((amdgpu_waves_per_eu(2,2)))
void lstm_wv(
    const float* __restrict__ whhf, const float* __restrict__ whhb,
    const float* __restrict__ bihf, const float* __restrict__ bhhf,
    const float* __restrict__ bihb, const float* __restrict__ bhhb,
    const float* __restrict__ h0f, const float* __restrict__ c0f,
    const float* __restrict__ h0b, const float* __restrict__ c0b,
    const float* __restrict__ xg,
    float* __restrict__ H, u64* hbuf)
{
  const int b = blockIdx.x;
  const int d = b >> 5;
  const int k = b & 31;
  const int tid = threadIdx.x;
  const int w = tid >> 6;
  const int l = tid & 63;
  const int u0 = k*16 + w*2;            // this wave's two units

  const float* whh = d ? whhb : whhf;
  // gate rows j=0..7: row_j = (j&3)*512 + u0 + (j>>2)  (unit-major, i,f,g,o)
#define ROWIX(j) (((j)&3)*512 + u0 + ((j)>>2))
#define ROWP(j)  (whh + (size_t)ROWIX(j)*512 + l*8)

  f32x16 W0, W1, W2, W3;
  {
    const float4* p0=(const float4*)ROWP(0); const float4* p1=(const float4*)ROWP(1);
    float4 a=p0[0], bb=p0[1], cc=p1[0], e=p1[1];
    W0 = (f32x16){a.x,a.y,a.z,a.w,bb.x,bb.y,bb.z,bb.w, cc.x,cc.y,cc.z,cc.w, e.x,e.y,e.z,e.w};
  }
  {
    const float4* p0=(const float4*)ROWP(2); const float4* p1=(const float4*)ROWP(3);
    float4 a=p0[0], bb=p0[1], cc=p1[0], e=p1[1];
    W1 = (f32x16){a.x,a.y,a.z,a.w,bb.x,bb.y,bb.z,bb.w, cc.x,cc.y,cc.z,cc.w, e.x,e.y,e.z,e.w};
  }
  {
    const float4* p0=(const float4*)ROWP(4); const float4* p1=(const float4*)ROWP(5);
    float4 a=p0[0], bb=p0[1], cc=p1[0], e=p1[1];
    W2 = (f32x16){a.x,a.y,a.z,a.w,bb.x,bb.y,bb.z,bb.w, cc.x,cc.y,cc.z,cc.w, e.x,e.y,e.z,e.w};
  }
  {
    const float4* p0=(const float4*)ROWP(6); const float4* p1=(const float4*)ROWP(7);
    float4 a=p0[0], bb=p0[1], cc=p1[0], e=p1[1];
    W3 = (f32x16){a.x,a.y,a.z,a.w,bb.x,bb.y,bb.z,bb.w, cc.x,cc.y,cc.z,cc.w, e.x,e.y,e.z,e.w};
  }

  const float* bih = d ? bihb : bihf;
  const float* bhh = d ? bhhb : bhhf;
  const float bs0 = bih[ROWIX(0)] + bhh[ROWIX(0)];
  const float bs1 = bih[ROWIX(1)] + bhh[ROWIX(1)];
  const float bs2 = bih[ROWIX(2)] + bhh[ROWIX(2)];
  const float bs3 = bih[ROWIX(3)] + bhh[ROWIX(3)];
  const float bs4 = bih[ROWIX(4)] + bhh[ROWIX(4)];
  const float bs5 = bih[ROWIX(5)] + bhh[ROWIX(5)];
  const float bs6 = bih[ROWIX(6)] + bhh[ROWIX(6)];
  const float bs7 = bih[ROWIX(7)] + bhh[ROWIX(7)];

  const float* h0p = d ? h0b : h0f;
  const float* c0p = d ? c0b : c0f;
  float4 hA = *(const float4*)(h0p + l*8);
  float4 hB = *(const float4*)(h0p + l*8 + 4);
  float hv0=hA.x, hv1=hA.y, hv2=hA.z, hv3=hA.w;
  float hv4=hB.x, hv5=hB.y, hv6=hB.z, hv7=hB.w;
  float cv0 = c0p[u0], cv1 = c0p[u0+1];

  // xg broadcast values live in lanes 0..7 (lane j holds row_j); depth-2.
  const float* xgp = xg + (size_t)d*8192*2048;
  const int xrow = ((l&3)<<9) + u0 + ((l>>2)&1);
  float xq0 = xgp[(size_t)(d?8191:0)*2048 + xrow];
  float xq1 = xgp[(size_t)(d?8190:1)*2048 + xrow];

#define DOTROW(ACC, W, O) \
  ACC=fmaf(hv0,W[O+0],ACC); ACC=fmaf(hv1,W[O+1],ACC); ACC=fmaf(hv2,W[O+2],ACC); ACC=fmaf(hv3,W[O+3],ACC); \
  ACC=fmaf(hv4,W[O+4],ACC); ACC=fmaf(hv5,W[O+5],ACC); ACC=fmaf(hv6,W[O+6],ACC); ACC=fmaf(hv7,W[O+7],ACC);
#define RED(OFF) \
  a0+=__shfl_xor(a0,OFF); a1+=__shfl_xor(a1,OFF); a2+=__shfl_xor(a2,OFF); a3+=__shfl_xor(a3,OFF); \
  a4+=__shfl_xor(a4,OFF); a5+=__shfl_xor(a5,OFF); a6+=__shfl_xor(a6,OFF); a7+=__shfl_xor(a7,OFF);

  for (int s=0; s<8192; s++){
    // loop-carried pin: weights stay true VGPRs (r6-verified combo)
    asm volatile("" : "+v"(W0), "+v"(W1), "+v"(W2), "+v"(W3));
    const int t  = d ? (8191-s) : s;
    const int pb = s & 1;

    float a0=0.f,a1=0.f,a2=0.f,a3=0.f,a4=0.f,a5=0.f,a6=0.f,a7=0.f;
    DOTROW(a0,W0,0) DOTROW(a1,W0,8)
    DOTROW(a2,W1,0) DOTROW(a3,W1,8)
    DOTROW(a4,W2,0) DOTROW(a5,W2,8)
    DOTROW(a6,W3,0) DOTROW(a7,W3,8)
    RED(1) RED(2) RED(4) RED(8) RED(16) RED(32)

    const float s0 = a0 + bs0 + rl(xq0,0);
    const float s1 = a1 + bs1 + rl(xq0,1);
    const float s2 = a2 + bs2 + rl(xq0,2);
    const float s3 = a3 + bs3 + rl(xq0,3);
    const float s4 = a4 + bs4 + rl(xq0,4);
    const float s5 = a5 + bs5 + rl(xq0,5);
    const float s6 = a6 + bs6 + rl(xq0,6);
    const float s7 = a7 + bs7 + rl(xq0,7);
    // gate math identical to rounds 2-8 (sigmoid; tanh via 2*sig(2x)-1)
    const float i0 = 1.f/(1.f+expf(-s0));
    const float f0 = 1.f/(1.f+expf(-s1));
    const float g0 = fmaf(2.f, 1.f/(1.f+expf(-2.f*s2)), -1.f);
    const float o0 = 1.f/(1.f+expf(-s3));
    cv0 = fmaf(f0, cv0, i0*g0);
    const float h0v = o0 * tanhf(cv0);
    const float i1 = 1.f/(1.f+expf(-s4));
    const float f1 = 1.f/(1.f+expf(-s5));
    const float g1 = fmaf(2.f, 1.f/(1.f+expf(-2.f*s6)), -1.f);
    const float o1 = 1.f/(1.f+expf(-s7));
    cv1 = fmaf(f1, cv1, i1*g1);
    const float h1v = o1 * tanhf(cv1);

    const u64 pk0 = ((u64)(unsigned)(s+1)<<32) | (u64)__float_as_uint(h0v);
    const u64 pk1 = ((u64)(unsigned)(s+1)<<32) | (u64)__float_as_uint(h1v);
    u64* hq = hbuf + (pb<<10) + d*512 + u0;
    if (l==0){
      __hip_atomic_store(hq,   pk0, __ATOMIC_RELAXED, __HIP_MEMORY_SCOPE_AGENT);
      __hip_atomic_store(hq+1, pk1, __ATOMIC_RELAXED, __HIP_MEMORY_SCOPE_AGENT);
    } else if (l==1){
      float2 hh; hh.x = h0v; hh.y = h1v;
      *reinterpret_cast<float2*>(H + (size_t)t*1024 + d*512 + u0) = hh;
    }

    // depth-2 xg prefetch (in flight during the poll)
    xq0 = xq1;
    if (s<8190) xq1 = xgp[(size_t)(d?(8189-s):(s+2))*2048 + xrow];

    if (s<8191){
      const u64* hp = hbuf + (pb<<10) + d*512 + l*8;
      const unsigned want = (unsigned)(s+1);
      u64 p0,p1,p2,p3,p4,p5,p6,p7;
      int it = 0;
      for (;;){
        p0 = __hip_atomic_load(hp+0, __ATOMIC_RELAXED, __HIP_MEMORY_SCOPE_AGENT);
        p1 = __hip_atomic_load(hp+1, __ATOMIC_RELAXED, __HIP_MEMORY_SCOPE_AGENT);
        p2 = __hip_atomic_load(hp+2, __ATOMIC_RELAXED, __HIP_MEMORY_SCOPE_AGENT);
        p3 = __hip_atomic_load(hp+3, __ATOMIC_RELAXED, __HIP_MEMORY_SCOPE_AGENT);
        p4 = __hip_atomic_load(hp+4, __ATOMIC_RELAXED, __HIP_MEMORY_SCOPE_AGENT);
        p5 = __hip_atomic_load(hp+5, __ATOMIC_RELAXED, __HIP_MEMORY_SCOPE_AGENT);
        p6 = __hip_atomic_load(hp+6, __ATOMIC_RELAXED, __HIP_MEMORY_SCOPE_AGENT);
        p7 = __hip_atomic_load(hp+7, __ATOMIC_RELAXED, __HIP_MEMORY_SCOPE_AGENT);
        const bool ok = (unsigned)(p0>>32)>=want && (unsigned)(p1>>32)>=want
                     && (unsigned)(p2>>32)>=want && (unsigned)(p3>>32)>=want
                     && (unsigned)(p4>>32)>=want && (unsigned)(p5>>32)>=want
                     && (unsigned)(p6>>32)>=want && (unsigned)(p7>>32)>=want;
        if (ok) break;
        if (++it > 4) __builtin_amdgcn_s_sleep(1);
      }
      hv0 = __uint_as_float((unsigned)p0);
      hv1 = __uint_as_float((unsigned)p1);
      hv2 = __uint_as_float((unsigned)p2);
      hv3 = __uint_as_float((unsigned)p3);
      hv4 = __uint_as_float((unsigned)p4);
      hv5 = __uint_as_float((unsigned)p5);
      hv6 = __uint_as_float((unsigned)p6);
      hv7 = __uint_as_float((unsigned)p7);
    }
  }
#undef DOTROW
#undef RED
#undef ROWP
#undef ROWIX
}

// =====================================================================
// K3: feats[t][n] = H[t][:] . w_tag[n][:] + b_tag[n]
// =====================================================================
__global__ void feats_k(const float* __restrict__ H, const float* __restrict__ wtag,
                        const float* __restrict__ btag, float* __restrict__ feats)
{
  const int r = blockIdx.x*4 + (threadIdx.x>>6);
  const int l = threadIdx.x & 63;
  const float* hrow = H + (size_t)r*1024;
  float hv[16];
  #pragma unroll
  for (int j=0;j<16;j++) hv[j] = hrow[j*64 + l];
  #pragma unroll
  for (int n=0;n<5;n++){
    const float* wrow = wtag + n*1024;
    float acc = 0.f;
    #pragma unroll
    for (int j=0;j<16;j++) acc = fmaf(hv[j], wrow[j*64+l], acc);
    #pragma unroll
    for (int off=32; off; off>>=1) acc += __shfl_xor(acc, off);
    if (l==0) feats[r*5+n] = acc + btag[n];
  }
}

// =====================================================================
// V: sequential Viterbi forward (exact fp32, reference association order).
// =====================================================================
__global__ void vit_fv(const float* __restrict__ feats, const float* __restrict__ trans,
                       int* __restrict__ bps, float* __restrict__ out, int* __restrict__ ebest)
{
  const int l = threadIdx.x & 63;
  const bool active = (l < 25);
  const int n = l/5;
  float tr0=0,tr1=0,tr2=0,tr3=0,tr4=0;
  if (active){ tr0=trans[n*5+0]; tr1=trans[n*5+1]; tr2=trans[n*5+2]; tr3=trans[n*5+3]; tr4=trans[n*5+4]; }
  const float NEG = -10000.0f;
  float fv0=NEG, fv1=NEG, fv2=NEG, fv3=0.f, fv4=NEG;   // START=3

  float ring[16];
  #pragma unroll
  for (int j=0;j<16;j++) ring[j] = active ? feats[j*5+n] : 0.f;

  for (int tb=0; tb<8192; tb+=16){
    #pragma unroll
    for (int j=0;j<16;j++){
      const int t = tb + j;
      float ft = ring[j];
      float m = fv0 + tr0; int a = 0; float v;
      v = fv1 + tr1; if (v > m){ m=v; a=1; }
      v = fv2 + tr2; if (v > m){ m=v; a=2; }
      v = fv3 + tr3; if (v > m){ m=v; a=3; }
      v = fv4 + tr4; if (v > m){ m=v; a=4; }
      float fnew = m + ft;
      if (active && (l%5)==0) bps[t*5+n] = a;
      fv0 = __shfl(fnew, 0);  fv1 = __shfl(fnew, 5);  fv2 = __shfl(fnew, 10);
      fv3 = __shfl(fnew, 15); fv4 = __shfl(fnew, 20);
      const int tf = t + 16;
      ring[j] = (active && tf < 8192) ? feats[tf*5+n] : 0.f;
    }
  }
  if (l==0){
    float t0=trans[20], t1=trans[21], t2=trans[22], t3=trans[23], t4=trans[24];
    float m = fv0 + t0; int a = 0; float v;
    v = fv1 + t1; if (v > m){ m=v; a=1; }
    v = fv2 + t2; if (v > m){ m=v; a=2; }
    v = fv3 + t3; if (v > m){ m=v; a=3; }
    v = fv4 + t4; if (v > m){ m=v; a=4; }
    out[0] = m;
    ebest[0] = a;
  }
}

// =====================================================================
// Backtrack: exact integer parallel scan over 256 chunks of 32 steps.
// =====================================================================
__global__ void bt_maps(const int* __restrict__ bps, int* __restrict__ Fc)
{
  __shared__ int sm[160];
  const int c = blockIdx.x, tid = threadIdx.x;
  for (int idx=tid; idx<160; idx+=64) sm[idx] = bps[c*160+idx];
  __syncthreads();
  if (tid<5){
    int cur = tid;
    for (int j=31;j>=0;j--) cur = sm[j*5+cur];
    Fc[c*5+tid] = cur;
  }
}

__global__ void bt_seq(const int* __restrict__ Fc, const int* __restrict__ ebest,
                       int* __restrict__ echunk)
{
  __shared__ int sm[1280];
  const int tid = threadIdx.x;
  for (int idx=tid; idx<1280; idx+=64) sm[idx]=Fc[idx];
  __syncthreads();
  if (tid==0){
    int e = ebest[0];
    for (int c=255;c>=0;c--){ echunk[c]=e; e = sm[c*5+e]; }
  }
}

__global__ void bt_emit(const int* __restrict__ bps, const int* __restrict__ echunk,
                        float* __restrict__ out)
{
  __shared__ int sm[160];
  const int c=blockIdx.x, tid=threadIdx.x;
  for (int idx=tid; idx<160; idx+=64) sm[idx]=bps[c*160+idx];
  __syncthreads();
  if (tid==0){
    int tag = echunk[c];
    out[1 + c*32 + 31] = (float)tag;
    for (int j=31;j>=1;j--){ tag = sm[j*5+tag]; out[1 + c*32 + j-1] = (float)tag; }
  }
}

// =====================================================================
extern "C" void kernel_launch(void* const* d_in, const int* in_sizes, int n_in,
                              void* d_out, int out_size, void* d_ws, size_t ws_size,
                              hipStream_t stream)
{
  (void)in_sizes; (void)n_in; (void)out_size;
  const float* emb  = (const float*)d_in[0];
  const float* wihf = (const float*)d_in[1];
  const float* whhf = (const float*)d_in[2];
  const float* bihf = (const float*)d_in[3];
  const float* bhhf = (const float*)d_in[4];
  const float* wihb = (const float*)d_in[5];
  const float* whhb = (const float*)d_in[6];
  const float* bihb = (const float*)d_in[7];
  const float* bhhb = (const float*)d_in[8];
  const float* wtag = (const float*)d_in[9];
  const float* btag = (const float*)d_in[10];
  const float* h0f  = (const float*)d_in[11];
  const float* c0f  = (const float*)d_in[12];
  const float* h0b  = (const float*)d_in[13];
  const float* c0b  = (const float*)d_in[14];
  const float* trans= (const float*)d_in[15];
  float* out = (float*)d_out;

  char* ws = (char*)d_ws;
  float* H      = (float*)(ws + OFF_H);
  float* feats  = (float*)(ws + OFF_FEATS);
  int*   bps    = (int*)  (ws + OFF_BPS);
  int*   Fc     = (int*)  (ws + OFF_FC);
  int*   echunk = (int*)  (ws + OFF_ECH);
  int*   ebest  = (int*)  (ws + OFF_EBEST);
  u64*   hbuf   = (u64*)  (ws + OFF_HBUF);
  float* xg     = (float*)(ws + OFF_XG);

  hipMemsetAsync(hbuf, 0, 16384, stream);   // clear (tag,h) pairs every launch

  xg_k<<<dim3(64,32), 256, 0, stream>>>(emb, wihf, wihb, xg);
  lstm_wv<<<64, 512, 0, stream>>>(whhf, whhb, bihf, bhhf, bihb, bhhb,
                                  h0f, c0f, h0b, c0b, xg, H, hbuf);
  feats_k<<<2048, 256, 0, stream>>>(H, wtag, btag, feats);
  vit_fv<<<1, 64, 0, stream>>>(feats, trans, bps, out, ebest);
  bt_maps<<<256, 64, 0, stream>>>(bps, Fc);
  bt_seq<<<1, 64, 0, stream>>>(Fc, ebest, echunk);
  bt_emit<<<256, 64, 0, stream>>>(bps, echunk, out);
}

// Round 10
// 13460.136 us; speedup vs baseline: 6.0145x; 6.0145x over previous
//
#include <hip/hip_runtime.h>
#include <hip/hip_bf16.h>
#include <math.h>

#define DEV static __device__ __forceinline__

DEV float rl(float v, int i){ return __uint_as_float(__builtin_amdgcn_readlane(__float_as_uint(v), i)); }

typedef float f32x16 __attribute__((ext_vector_type(16)));
typedef unsigned long long u64;

// ---- workspace layout (bytes) ----
static constexpr size_t OFF_H     = 0;                    // 8192*1024*4 = 33554432
static constexpr size_t OFF_FEATS = 33554432;             // 8192*5*4    = 163840
static constexpr size_t OFF_BPS   = OFF_FEATS + 163840;   // 8192*5*4 int
static constexpr size_t OFF_FC    = OFF_BPS + 163840;     // 256*5*4
static constexpr size_t OFF_ECH   = OFF_FC + 5120;        // 256*4
static constexpr size_t OFF_EBEST = OFF_ECH + 1024;       // 256
static constexpr size_t OFF_RC    = OFF_EBEST + 256;      // 64 ints (xg row flags), pad 256
static constexpr size_t OFF_HBUF  = OFF_RC + 256;         // 2*1024*8 = 16384
static constexpr size_t OFF_XG    = OFF_HBUF + 16384;     // 2*8192*2048*4
static constexpr size_t XG_BYTES  = 2ull*8192*2048*4;

#define DOT16(X, OFF, W, B0, B1_, B2_, B3_) \
  _Pragma("unroll") for (int i=0;i<16;i+=4){ \
    B0 =fmaf(rl(X,OFF+i+0),W[i+0],B0 ); B1_=fmaf(rl(X,OFF+i+1),W[i+1],B1_); \
    B2_=fmaf(rl(X,OFF+i+2),W[i+2],B2_); B3_=fmaf(rl(X,OFF+i+3),W[i+3],B3_); }

// =====================================================================
// xg tile worker: one 128x128 fp32 GEMM tile of xg[d][t][row] =
// emb . wih^T, computed by 256 threads (one sub-block). Stores are
// relaxed AGENT-scope u64 (write-through to MALL): per-XCD L2s are not
// cross-coherent, so normal (write-back) stores would strand dirty
// lines invisible to LSTM consumers on other XCDs. The trailing joint
// __syncthreads drains vmcnt(0) (acks at MALL) before the flag bump.
// =====================================================================
DEV void xg_tile(const float* __restrict__ emb, const float* __restrict__ wihf,
                 const float* __restrict__ wihb, float* __restrict__ xg,
                 int* rowcnt, int tm32, int tn32, bool doflag,
                 float (*As)[132], float (*Bs)[132], int tid)
{
  const int tmb = tm32*128, tnb = tn32*128;
  const int ty = tid >> 4, tx = tid & 15;
  float acc[8][8];
  #pragma unroll
  for (int i=0;i<8;i++)
    #pragma unroll
    for (int j=0;j<8;j++) acc[i][j] = 0.f;

  const int m  = tid & 127;
  const int n  = tnb + m;
  const float* wih = (n & 2048) ? wihb : wihf;
  const float* arow = emb + (size_t)(tmb+m)*768;
  const float* brow = wih + (size_t)(n&2047)*768;
  const int kq = (tid >> 7) << 2;

  for (int k0=0; k0<768; k0+=16){
    #pragma unroll
    for (int r=0;r<2;r++){
      const int kk = kq + r*8;
      float4 v = *reinterpret_cast<const float4*>(arow + k0 + kk);
      As[kk+0][m]=v.x; As[kk+1][m]=v.y; As[kk+2][m]=v.z; As[kk+3][m]=v.w;
      float4 u = *reinterpret_cast<const float4*>(brow + k0 + kk);
      Bs[kk+0][m]=u.x; Bs[kk+1][m]=u.y; Bs[kk+2][m]=u.z; Bs[kk+3][m]=u.w;
    }
    __syncthreads();   // joint 512-thread barrier (both sub-blocks aligned)
    #pragma unroll
    for (int kk2=0;kk2<16;kk2++){
      float4 a0 = *reinterpret_cast<const float4*>(&As[kk2][ty*8]);
      float4 a1 = *reinterpret_cast<const float4*>(&As[kk2][ty*8+4]);
      float4 b0 = *reinterpret_cast<const float4*>(&Bs[kk2][tx*8]);
      float4 b1 = *reinterpret_cast<const float4*>(&Bs[kk2][tx*8+4]);
      float af[8] = {a0.x,a0.y,a0.z,a0.w,a1.x,a1.y,a1.z,a1.w};
      float bf[8] = {b0.x,b0.y,b0.z,b0.w,b1.x,b1.y,b1.z,b1.w};
      #pragma unroll
      for (int i=0;i<8;i++)
        #pragma unroll
        for (int j=0;j<8;j++) acc[i][j] = fmaf(af[i], bf[j], acc[i][j]);
    }
    __syncthreads();
  }

  const int dd = tnb >> 11, nb = tnb & 2047;
  float* xgp = xg + (size_t)dd*8192*2048;
  #pragma unroll
  for (int i=0;i<8;i++){
    float* orow = xgp + (size_t)(tmb+ty*8+i)*2048 + nb + tx*8;
    #pragma unroll
    for (int j=0;j<8;j+=2){
      u64 uu = ((u64)__float_as_uint(acc[i][j+1])<<32) | (u64)__float_as_uint(acc[i][j]);
      __hip_atomic_store(reinterpret_cast<u64*>(orow + j), uu,
                         __ATOMIC_RELAXED, __HIP_MEMORY_SCOPE_AGENT);
    }
  }
  __syncthreads();   // implies s_waitcnt vmcnt(0): agent stores acked at MALL
  if (doflag && tid==0)
    __hip_atomic_fetch_add(rowcnt + tm32, 1, __ATOMIC_RELAXED, __HIP_MEMORY_SCOPE_AGENT);
}

DEV void wait_row(const int* rc, int tm){
  while (__hip_atomic_load(rc + tm, __ATOMIC_RELAXED, __HIP_MEMORY_SCOPE_AGENT) < 32)
    __builtin_amdgcn_s_sleep(8);
  __builtin_amdgcn_sched_barrier(0);
  asm volatile("" ::: "memory");
}

// =====================================================================
// fused_k: 256 blocks x 512 threads (1 block/CU, all co-resident).
//  - blocks 0..63: the round-5 persistent BiLSTM verbatim (12.3ms,
//    step 1.5us — the proven agent-scope tag-in-data sync; rounds 6-9
//    showed the rendezvous ~1.2us/step is the floor). Only changes:
//    xg prefetch gated on per-row ready flags (once per 128 steps) and
//    poll sleeps only after 4 failed spins.
//  - blocks 64..255: 384 xg-GEMM workers (2 sub-tiles/block), tiles
//    ordered both-ends-first (fwd consumes t ascending, bwd descending).
//    Production ~9x faster than consumption -> one-time ~150us stall.
//    This removes the ~1ms serial xg_k from the critical path.
// =====================================================================
__global__ __launch_bounds__(512,2) void fused_k(
    const float* __restrict__ emb,
    const float* __restrict__ wihf, const float* __restrict__ wihb,
    const float* __restrict__ whhf, const float* __restrict__ whhb,
    const float* __restrict__ bihf, const float* __restrict__ bhhf,
    const float* __restrict__ bihb, const float* __restrict__ bhhb,
    const float* __restrict__ h0f, const float* __restrict__ c0f,
    const float* __restrict__ h0b, const float* __restrict__ c0b,
    float* __restrict__ xg, float* __restrict__ H,
    u64* __restrict__ hbuf, int* __restrict__ rowcnt)
{
  __shared__ float smemf[8448];   // workers: 2 x (As[16][132]+Bs[16][132]); lstm: part[2][8][64]
  const int b = blockIdx.x;

  if (b >= 64){
    // ---------------- xg worker ----------------
    const int tid = threadIdx.x & 255;
    const int sb  = threadIdx.x >> 8;
    float (*As)[132] = (float(*)[132])(smemf + sb*4224);
    float (*Bs)[132] = (float(*)[132])(smemf + sb*4224 + 2112);
    const int wkr = (b - 64)*2 + sb;          // 0..383
    for (int r=0; r<6; r++){                  // 6 rounds covers 2048 jobs; fixed trip for barrier alignment
      int j = wkr + r*384;
      const bool real = (j < 2048);
      if (!real) j = 2047;                    // dummy recompute (same values, flag skipped)
      const int p = j >> 5, tn32 = j & 31;
      const int tm32 = (p & 1) ? (63 - (p>>1)) : (p>>1);   // 0,63,1,62,...
      xg_tile(emb, wihf, wihb, xg, rowcnt, tm32, tn32, real, As, Bs, tid);
    }
    return;
  }

  // ---------------- LSTM role (round-5 body) ----------------
  float (*part)[8][64] = (float(*)[8][64])smemf;   // [2][8][64]
  const int d  = b >> 5;
  const int k  = b & 31;
  const int tid = threadIdx.x;
  const int w  = tid >> 6;
  const int l  = tid & 63;

  const float* whh = d ? whhb : whhf;
  const int grow = (l&3)*512 + k*16 + (l>>2);

  const float* pr = whh + (size_t)grow*512 + w*64;
  f32x16 wr0 = *reinterpret_cast<const f32x16*>(pr);
  f32x16 wr1 = *reinterpret_cast<const f32x16*>(pr+16);
  f32x16 wr2 = *reinterpret_cast<const f32x16*>(pr+32);
  f32x16 wr3 = *reinterpret_cast<const f32x16*>(pr+48);

  const float bias = (d?bihb:bihf)[grow] + (d?bhhb:bhhf)[grow];
  const float* xgp = xg + (size_t)d*8192*2048;

  const float* h0 = d ? h0b : h0f;
  float hv = h0[w*64 + l];
  float c  = (d?c0b:c0f)[k*16 + (l>>2)];

  float xq0 = 0.f, xq1 = 0.f;
  if (w==0){
    wait_row(rowcnt, d ? 63 : 0);           // gate the prologue tile
    xq0 = xgp[(size_t)(d?8191:0)*2048 + grow];
    xq1 = xgp[(size_t)(d?8190:1)*2048 + grow];
  }

  for (int s=0; s<8192; s++){
    const int t  = d ? (8191-s) : s;
    const int pb = s & 1;
    float a0=0.f, a1=0.f, a2=0.f, a3=0.f;
    DOT16(hv, 0, wr0, a0,a1,a2,a3)
    DOT16(hv,16, wr1, a0,a1,a2,a3)
    DOT16(hv,32, wr2, a0,a1,a2,a3)
    DOT16(hv,48, wr3, a0,a1,a2,a3)
    part[pb][w][l] = (a0+a1)+(a2+a3);
    __syncthreads();

    if (w==0){
      float r = ((part[pb][0][l]+part[pb][1][l])+(part[pb][2][l]+part[pb][3][l]))
              + ((part[pb][4][l]+part[pb][5][l])+(part[pb][6][l]+part[pb][7][l]))
              + bias + xq0;
      const bool isg = ((l&3)==2);
      float xx = isg ? 2.f*r : r;
      float sg = 1.f/(1.f + expf(-xx));        // sigmoid
      float a  = isg ? fmaf(2.f,sg,-1.f) : sg; // tanh via 2*sig(2x)-1 for g-gate
      const int lb = l & ~3;
      float ig = __shfl(a, lb);
      float fg = __shfl(a, lb+1);
      float gg = __shfl(a, lb+2);
      float og = __shfl(a, lb+3);
      if ((l&3)==0){
        c = fmaf(fg, c, ig*gg);
        float h = og * tanhf(c);
        const int unit = k*16 + (l>>2);
        u64 pk = ((u64)(unsigned)(s+1) << 32) | (u64)__float_as_uint(h);
        __hip_atomic_store(hbuf + (pb<<10) + d*512 + unit, pk,
                           __ATOMIC_RELAXED, __HIP_MEMORY_SCOPE_AGENT);
        H[(size_t)t*1024 + d*512 + unit] = h;
      }
      // depth-2 xg prefetch for t(s+2), gated at 128-row tile boundaries
      xq0 = xq1;
      if (s<8190){
        const int t2 = d ? (8189-s) : (s+2);
        if (d==0 ? ((t2 & 127)==0) : ((t2 & 127)==127)) wait_row(rowcnt, t2>>7);
        xq1 = xgp[(size_t)t2*2048 + grow];
      }
    }

    if (s<8191){
      const u64* hp = hbuf + (pb<<10) + d*512 + w*64 + l;
      const unsigned want = (unsigned)(s+1);
      u64 p0 = __hip_atomic_load(hp, __ATOMIC_RELAXED, __HIP_MEMORY_SCOPE_AGENT);
      int it = 0;
      while ((unsigned)(p0>>32) < want){
        if (++it > 4) __builtin_amdgcn_s_sleep(1);   // tight first spins
        p0 = __hip_atomic_load(hp, __ATOMIC_RELAXED, __HIP_MEMORY_SCOPE_AGENT);
      }
      hv = __uint_as_float((unsigned)p0);
    }
  }
}

// =====================================================================
// Legacy fallback (round-4/5 single-kernel path) — only if ws too small.
// =====================================================================
__global__ __launch_bounds__(512,2) void lstm_legacy(
    const float* __restrict__ emb,
    const float* __restrict__ whhf, const float* __restrict__ whhb,
    const float* __restrict__ wihf, const float* __restrict__ wihb,
    const float* __restrict__ bihf, const float* __restrict__ bhhf,
    const float* __restrict__ bihb, const float* __restrict__ bhhb,
    const float* __restrict__ h0f, const float* __restrict__ c0f,
    const float* __restrict__ h0b, const float* __restrict__ c0b,
    float* __restrict__ H, u64* __restrict__ hbuf)
{
  const int b  = blockIdx.x;
  const int d  = b >> 5;
  const int k  = b & 31;
  const int tid = threadIdx.x;
  const int w  = tid >> 6;
  const int l  = tid & 63;

  const float* whh = d ? whhb : whhf;
  const float* wih = d ? wihb : wihf;
  const int grow = (l&3)*512 + k*16 + (l>>2);

  const float* pr = whh + (size_t)grow*512 + w*64;
  f32x16 wr0 = *reinterpret_cast<const f32x16*>(pr);
  f32x16 wr1 = *reinterpret_cast<const f32x16*>(pr+16);
  f32x16 wr2 = *reinterpret_cast<const f32x16*>(pr+32);
  f32x16 wr3 = *reinterpret_cast<const f32x16*>(pr+48);
  const float* pi = wih + (size_t)grow*768 + w*96;
  f32x16 wi0 = *reinterpret_cast<const f32x16*>(pi);
  f32x16 wi1 = *reinterpret_cast<const f32x16*>(pi+16);
  f32x16 wi2 = *reinterpret_cast<const f32x16*>(pi+32);
  f32x16 wi3 = *reinterpret_cast<const f32x16*>(pi+48);
  f32x16 wi4 = *reinterpret_cast<const f32x16*>(pi+64);
  f32x16 wi5 = *reinterpret_cast<const f32x16*>(pi+80);

  const float bias = (d?bihb:bihf)[grow] + (d?bhhb:bhhf)[grow];
  const float* h0 = d ? h0b : h0f;
  float hv = h0[w*64 + l];
  float c  = (d?c0b:c0f)[k*16 + (l>>2)];

  __shared__ float part[2][8][64];

#define EPART(X0,X1,B0,B1_,B2_,B3_) \
  DOT16(X0, 0, wi0, B0,B1_,B2_,B3_) DOT16(X0,16, wi1, B0,B1_,B2_,B3_) \
  DOT16(X0,32, wi2, B0,B1_,B2_,B3_) DOT16(X0,48, wi3, B0,B1_,B2_,B3_) \
  DOT16(X1, 0, wi4, B0,B1_,B2_,B3_) DOT16(X1,16, wi5, B0,B1_,B2_,B3_)

  float acc_e;
  {
    const int tA = d ? 8191 : 0;
    const float* e = emb + (size_t)tA*768 + w*96 + l;
    float x0 = e[0];
    float x1 = (l<32) ? e[64] : 0.f;
    float b0=0.f,b1=0.f,b2=0.f,b3=0.f;
    EPART(x0,x1,b0,b1,b2,b3);
    acc_e = (b0+b1)+(b2+b3);
  }
  float ev0, ev1;
  {
    const int tB = d ? 8190 : 1;
    const float* e = emb + (size_t)tB*768 + w*96 + l;
    ev0 = e[0];
    ev1 = (l<32) ? e[64] : 0.f;
  }

  for (int s=0; s<8192; s++){
    const int t  = d ? (8191-s) : s;
    const int pb = s & 1;
    float a0=acc_e, a1=0.f, a2=0.f, a3=0.f;
    DOT16(hv, 0, wr0, a0,a1,a2,a3)
    DOT16(hv,16, wr1, a0,a1,a2,a3)
    DOT16(hv,32, wr2, a0,a1,a2,a3)
    DOT16(hv,48, wr3, a0,a1,a2,a3)
    part[pb][w][l] = (a0+a1)+(a2+a3);
    __syncthreads();

    if (w==0){
      float r = ((part[pb][0][l]+part[pb][1][l])+(part[pb][2][l]+part[pb][3][l]))
              + ((part[pb][4][l]+part[pb][5][l])+(part[pb][6][l]+part[pb][7][l])) + bias;
      const bool isg = ((l&3)==2);
      float xx = isg ? 2.f*r : r;
      float sg = 1.f/(1.f + expf(-xx));
      float a  = isg ? fmaf(2.f,sg,-1.f) : sg;
      const int lb = l & ~3;
      float ig = __shfl(a, lb);
      float fg = __shfl(a, lb+1);
      float gg = __shfl(a, lb+2);
      float og = __shfl(a, lb+3);
      if ((l&3)==0){
        c = fmaf(fg, c, ig*gg);
        float h = og * tanhf(c);
        const int unit = k*16 + (l>>2);
        u64 pk = ((u64)(unsigned)(s+1) << 32) | (u64)__float_as_uint(h);
        __hip_atomic_store(hbuf + (pb<<10) + d*512 + unit, pk,
                           __ATOMIC_RELAXED, __HIP_MEMORY_SCOPE_AGENT);
        H[(size_t)t*1024 + d*512 + unit] = h;
      }
    }

    if (s<8191){
      float nx0=0.f, nx1=0.f;
      if (s<8190){
        const int t2 = d ? (8189-s) : (s+2);
        const float* e = emb + (size_t)t2*768 + w*96 + l;
        nx0 = e[0];
        nx1 = (l<32) ? e[64] : 0.f;
      }
      float b0=0.f,b1=0.f,b2=0.f,b3=0.f;
      EPART(ev0,ev1,b0,b1,b2,b3);
      acc_e = (b0+b1)+(b2+b3);
      ev0=nx0; ev1=nx1;

      const u64* hp = hbuf + (pb<<10) + d*512 + w*64 + l;
      const unsigned want = (unsigned)(s+1);
      u64 p0 = __hip_atomic_load(hp, __ATOMIC_RELAXED, __HIP_MEMORY_SCOPE_AGENT);
      while ((unsigned)(p0>>32) < want){
        __builtin_amdgcn_s_sleep(1);
        p0 = __hip_atomic_load(hp, __ATOMIC_RELAXED, __HIP_MEMORY_SCOPE_AGENT);
      }
      hv = __uint_as_float((unsigned)p0);
    }
  }
#undef EPART
}

// =====================================================================
// K3: feats[t][n] = H[t][:] . w_tag[n][:] + b_tag[n]
// =====================================================================
__global__ void feats_k(const float* __restrict__ H, const float* __restrict__ wtag,
                        const float* __restrict__ btag, float* __restrict__ feats)
{
  const int r = blockIdx.x*4 + (threadIdx.x>>6);
  const int l = threadIdx.x & 63;
  const float* hrow = H + (size_t)r*1024;
  float hv[16];
  #pragma unroll
  for (int j=0;j<16;j++) hv[j] = hrow[j*64 + l];
  #pragma unroll
  for (int n=0;n<5;n++){
    const float* wrow = wtag + n*1024;
    float acc = 0.f;
    #pragma unroll
    for (int j=0;j<16;j++) acc = fmaf(hv[j], wrow[j*64+l], acc);
    #pragma unroll
    for (int off=32; off; off>>=1) acc += __shfl_xor(acc, off);
    if (l==0) feats[r*5+n] = acc + btag[n];
  }
}

// =====================================================================
// V: sequential Viterbi forward (exact fp32, reference association order).
// =====================================================================
__global__ void vit_fv(const float* __restrict__ feats, const float* __restrict__ trans,
                       int* __restrict__ bps, float* __restrict__ out, int* __restrict__ ebest)
{
  const int l = threadIdx.x & 63;
  const bool active = (l < 25);
  const int n = l/5;
  float tr0=0,tr1=0,tr2=0,tr3=0,tr4=0;
  if (active){ tr0=trans[n*5+0]; tr1=trans[n*5+1]; tr2=trans[n*5+2]; tr3=trans[n*5+3]; tr4=trans[n*5+4]; }
  const float NEG = -10000.0f;
  float fv0=NEG, fv1=NEG, fv2=NEG, fv3=0.f, fv4=NEG;   // START=3

  float ring[16];
  #pragma unroll
  for (int j=0;j<16;j++) ring[j] = active ? feats[j*5+n] : 0.f;

  for (int tb=0; tb<8192; tb+=16){
    #pragma unroll
    for (int j=0;j<16;j++){
      const int t = tb + j;
      float ft = ring[j];
      float m = fv0 + tr0; int a = 0; float v;
      v = fv1 + tr1; if (v > m){ m=v; a=1; }
      v = fv2 + tr2; if (v > m){ m=v; a=2; }
      v = fv3 + tr3; if (v > m){ m=v; a=3; }
      v = fv4 + tr4; if (v > m){ m=v; a=4; }
      float fnew = m + ft;
      if (active && (l%5)==0) bps[t*5+n] = a;
      fv0 = __shfl(fnew, 0);  fv1 = __shfl(fnew, 5);  fv2 = __shfl(fnew, 10);
      fv3 = __shfl(fnew, 15); fv4 = __shfl(fnew, 20);
      const int tf = t + 16;
      ring[j] = (active && tf < 8192) ? feats[tf*5+n] : 0.f;
    }
  }
  if (l==0){
    float t0=trans[20], t1=trans[21], t2=trans[22], t3=trans[23], t4=trans[24];
    float m = fv0 + t0; int a = 0; float v;
    v = fv1 + t1; if (v > m){ m=v; a=1; }
    v = fv2 + t2; if (v > m){ m=v; a=2; }
    v = fv3 + t3; if (v > m){ m=v; a=3; }
    v = fv4 + t4; if (v > m){ m=v; a=4; }
    out[0] = m;
    ebest[0] = a;
  }
}

// =====================================================================
// Backtrack: exact integer parallel scan over 256 chunks of 32 steps.
// =====================================================================
__global__ void bt_maps(const int* __restrict__ bps, int* __restrict__ Fc)
{
  __shared__ int sm[160];
  const int c = blockIdx.x, tid = threadIdx.x;
  for (int idx=tid; idx<160; idx+=64) sm[idx] = bps[c*160+idx];
  __syncthreads();
  if (tid<5){
    int cur = tid;
    for (int j=31;j>=0;j--) cur = sm[j*5+cur];
    Fc[c*5+tid] = cur;
  }
}

__global__ void bt_seq(const int* __restrict__ Fc, const int* __restrict__ ebest,
                       int* __restrict__ echunk)
{
  __shared__ int sm[1280];
  const int tid = threadIdx.x;
  for (int idx=tid; idx<1280; idx+=64) sm[idx]=Fc[idx];
  __syncthreads();
  if (tid==0){
    int e = ebest[0];
    for (int c=255;c>=0;c--){ echunk[c]=e; e = sm[c*5+e]; }
  }
}

__global__ void bt_emit(const int* __restrict__ bps, const int* __restrict__ echunk,
                        float* __restrict__ out)
{
  __shared__ int sm[160];
  const int c=blockIdx.x, tid=threadIdx.x;
  for (int idx=tid; idx<160; idx+=64) sm[idx]=bps[c*160+idx];
  __syncthreads();
  if (tid==0){
    int tag = echunk[c];
    out[1 + c*32 + 31] = (float)tag;
    for (int j=31;j>=1;j--){ tag = sm[j*5+tag]; out[1 + c*32 + j-1] = (float)tag; }
  }
}

// =====================================================================
extern "C" void kernel_launch(void* const* d_in, const int* in_sizes, int n_in,
                              void* d_out, int out_size, void* d_ws, size_t ws_size,
                              hipStream_t stream)
{
  (void)in_sizes; (void)n_in; (void)out_size;
  const float* emb  = (const float*)d_in[0];
  const float* wihf = (const float*)d_in[1];
  const float* whhf = (const float*)d_in[2];
  const float* bihf = (const float*)d_in[3];
  const float* bhhf = (const float*)d_in[4];
  const float* wihb = (const float*)d_in[5];
  const float* whhb = (const float*)d_in[6];
  const float* bihb = (const float*)d_in[7];
  const float* bhhb = (const float*)d_in[8];
  const float* wtag = (const float*)d_in[9];
  const float* btag = (const float*)d_in[10];
  const float* h0f  = (const float*)d_in[11];
  const float* c0f  = (const float*)d_in[12];
  const float* h0b  = (const float*)d_in[13];
  const float* c0b  = (const float*)d_in[14];
  const float* trans= (const float*)d_in[15];
  float* out = (float*)d_out;

  char* ws = (char*)d_ws;
  float* H      = (float*)(ws + OFF_H);
  float* feats  = (float*)(ws + OFF_FEATS);
  int*   bps    = (int*)  (ws + OFF_BPS);
  int*   Fc     = (int*)  (ws + OFF_FC);
  int*   echunk = (int*)  (ws + OFF_ECH);
  int*   ebest  = (int*)  (ws + OFF_EBEST);
  int*   rowcnt = (int*)  (ws + OFF_RC);
  u64*   hbuf   = (u64*)  (ws + OFF_HBUF);
  float* xg     = (float*)(ws + OFF_XG);

  // reset row flags + (tag,h) pairs every launch (graph-replay safe)
  hipMemsetAsync(rowcnt, 0, 256 + 16384, stream);

  const bool use_xg = ws_size >= OFF_XG + XG_BYTES;
  if (use_xg){
    fused_k<<<256, 512, 0, stream>>>(emb, wihf, wihb, whhf, whhb,
                                     bihf, bhhf, bihb, bhhb,
                                     h0f, c0f, h0b, c0b, xg, H, hbuf, rowcnt);
  } else {
    lstm_legacy<<<64, 512, 0, stream>>>(emb, whhf, whhb, wihf, wihb,
                                        bihf, bhhf, bihb, bhhb,
                                        h0f, c0f, h0b, c0b, H, hbuf);
  }
  feats_k<<<2048, 256, 0, stream>>>(H, wtag, btag, feats);
  vit_fv<<<1, 64, 0, stream>>>(feats, trans, bps, out, ebest);
  bt_maps<<<256, 64, 0, stream>>>(bps, Fc);
  bt_seq<<<1, 64, 0, stream>>>(Fc, ebest, echunk);
  bt_emit<<<256, 64, 0, stream>>>(bps, echunk, out);
}